// Round 8
// baseline (252.602 us; speedup 1.0000x reference)
//
#include <hip/hip_runtime.h>
#include <hip/hip_bf16.h>

#define BB 64
#define TT 1024
#define CHN 256
#define VV 32000
#define EE 64
#define LL 128
#define NC1 250      // k1 k-chunks (250*128 = 32000)
#define KC1 128
#define TS 16        // attention t-chunks (64 t each)

typedef unsigned short u16;
typedef unsigned int u32;

__device__ __forceinline__ float fast_rcp(float x) { return __builtin_amdgcn_rcpf(x); }
__device__ __forceinline__ float tanh_fast(float y) {
    float e = __expf(2.0f * y);              // inf/0 limits give +-1 correctly
    return 1.0f - 2.0f * fast_rcp(1.0f + e);
}
__device__ __forceinline__ float sigmoid_fast(float x) {
    return fast_rcp(1.0f + __expf(-x));
}

// ---------------- K1: prev_char[64,32000] @ Wc[32000,64] -> part[b][kc][e] -----------
__global__ __launch_bounds__(256) void k1_stage1(const float* __restrict__ A,
                                                 const float* __restrict__ Wc,
                                                 float* __restrict__ part) {
    __shared__ float sW[KC1][EE];      // 32 KB
    __shared__ float sAT[KC1][32];     // 16 KB, transposed: [k][local_b]
    const int kc = blockIdx.x;
    const int k0 = kc * KC1;
    const int y  = blockIdx.y;
    const int t  = threadIdx.x;

    #pragma unroll
    for (int f = t; f < 2048; f += 256)
        *(float4*)(&sW[0][0] + f * 4) = *(const float4*)(Wc + (size_t)k0 * EE + f * 4);
    {
        const int bl = t & 31;
        const int kq = t >> 5;         // 0..7
        const float* src = A + (size_t)(y * 32 + bl) * VV + k0 + kq * 16;
        #pragma unroll
        for (int j4 = 0; j4 < 4; ++j4) {
            float4 v = *(const float4*)(src + j4 * 4);
            sAT[kq * 16 + j4 * 4 + 0][bl] = v.x;
            sAT[kq * 16 + j4 * 4 + 1][bl] = v.y;
            sAT[kq * 16 + j4 * 4 + 2][bl] = v.z;
            sAT[kq * 16 + j4 * 4 + 3][bl] = v.w;
        }
    }
    __syncthreads();

    const int e  = t & 63;
    const int b0 = (t >> 6) * 8;
    float acc[8];
    #pragma unroll
    for (int i = 0; i < 8; ++i) acc[i] = 0.0f;

    #pragma unroll 4
    for (int k = 0; k < KC1; ++k) {
        float wt = sW[k][e];
        float4 a0 = *(const float4*)&sAT[k][b0];           // uniform -> broadcast
        float4 a1 = *(const float4*)&sAT[k][b0 + 4];
        acc[0] = fmaf(a0.x, wt, acc[0]);
        acc[1] = fmaf(a0.y, wt, acc[1]);
        acc[2] = fmaf(a0.z, wt, acc[2]);
        acc[3] = fmaf(a0.w, wt, acc[3]);
        acc[4] = fmaf(a1.x, wt, acc[4]);
        acc[5] = fmaf(a1.y, wt, acc[5]);
        acc[6] = fmaf(a1.z, wt, acc[6]);
        acc[7] = fmaf(a1.w, wt, acc[7]);
    }
    const int gb = y * 32 + b0;
    #pragma unroll
    for (int i = 0; i < 8; ++i)
        part[((size_t)(gb + i) * NC1 + kc) * EE + e] = acc[i];
}

// ---------------- K2: reduce part + pcv@Wct1, z-GEMM, gates, H_tfm -------------------
__global__ __launch_bounds__(512) void k2_lstm(const float* __restrict__ part,
    const float* __restrict__ pcv, const float* __restrict__ state_h,
    const float* __restrict__ state_c, const float* __restrict__ Wct1,
    const float* __restrict__ lstm_kernel, const float* __restrict__ lstm_rec,
    const float* __restrict__ W_h,
    float* __restrict__ out_newh, float* __restrict__ out_newc,
    float* __restrict__ At, float* __restrict__ Htfm) {
    __shared__ float red[8][EE];
    __shared__ float inp[EE];
    __shared__ float sh[LL];
    __shared__ float z[4 * LL];
    __shared__ float nh[LL];
    const int b = blockIdx.x;
    const int t = threadIdx.x;
    const int e  = t & 63;
    const int g  = t >> 6;          // 0..7

    {
        float s = 0.0f;
        for (int j = g; j < NC1; j += 8)                       // contiguous 64KB window
            s += part[((size_t)b * NC1 + j) * EE + e];
        const int c0 = g * 32;
        #pragma unroll 8
        for (int c = 0; c < 32; ++c)
            s = fmaf(pcv[b * CHN + c0 + c], Wct1[(size_t)(c0 + c) * EE + e], s);
        red[g][e] = s;
    }
    __syncthreads();
    if (t < EE) {
        float s = 0.0f;
        #pragma unroll
        for (int j = 0; j < 8; ++j) s += red[j][t];
        inp[t] = s;
    } else if (t >= 64 && t < 64 + LL) {
        sh[t - 64] = state_h[b * LL + (t - 64)];
    }
    __syncthreads();
    {
        float a = 0.0f;
        #pragma unroll 8
        for (int e2 = 0; e2 < EE; ++e2) a = fmaf(inp[e2], lstm_kernel[e2 * 512 + t], a);
        #pragma unroll 8
        for (int l = 0; l < LL; ++l) a = fmaf(sh[l], lstm_rec[l * 512 + t], a);
        z[t] = a;
    }
    __syncthreads();
    if (t < LL) {
        float zi = z[t], zf = z[LL + t], zg = z[2 * LL + t], zo = z[3 * LL + t];
        float ig = sigmoid_fast(zi);
        float fg = sigmoid_fast(zf);
        float gg = tanh_fast(zg);
        float og = sigmoid_fast(zo);
        float co = state_c[b * LL + t];
        float cn = fg * co + ig * gg;
        float hn = og * tanh_fast(cn);
        out_newc[b * LL + t] = fminf(fmaxf(cn, -10.0f), 10.0f);
        out_newh[b * LL + t] = hn;
        At[t * BB + b] = hn;           // At[k][b] layout for k5
        nh[t] = hn;
    }
    __syncthreads();
    if (t < CHN) {
        float a = 0.0f;
        #pragma unroll 8
        for (int l = 0; l < LL; ++l) a = fmaf(nh[l], W_h[l * CHN + t], a);
        Htfm[b * CHN + t] = a;
    }
}

// ---------------- K3: attention partials per (b, ts) ---------------------------------
__global__ __launch_bounds__(256) void k3_attn(const float* __restrict__ F,
    const float* __restrict__ Htfm, const float* __restrict__ Vattn,
    float* __restrict__ pS, float* __restrict__ pW) {
    __shared__ float4 sS[256];
    __shared__ float4 sW[256];
    const int b    = blockIdx.x;
    const int ts   = blockIdx.y;
    const int lane = threadIdx.x & 63;
    const int w    = threadIdx.x >> 6;
    const int ch   = lane * 4;

    float4 h = *(const float4*)(Htfm + b * CHN + ch);
    float4 v = *(const float4*)(Vattn + ch);
    float s0 = 0, s1 = 0, s2 = 0, s3 = 0;
    float a0 = 0, a1 = 0, a2 = 0, a3 = 0;

    const float* Fp = F + ((size_t)b * TT + ts * (TT / TS) + w * 16) * CHN + ch;
    float4 cur = *(const float4*)(Fp);
    #pragma unroll
    for (int t = 0; t < 16; ++t) {
        float4 nxt;
        if (t < 15) nxt = *(const float4*)(Fp + (size_t)(t + 1) * CHN);
        float e0 = __expf(v.x * tanh_fast(h.x + cur.x));
        float e1 = __expf(v.y * tanh_fast(h.y + cur.y));
        float e2 = __expf(v.z * tanh_fast(h.z + cur.z));
        float e3 = __expf(v.w * tanh_fast(h.w + cur.w));
        s0 += e0; s1 += e1; s2 += e2; s3 += e3;
        a0 = fmaf(e0, cur.x, a0); a1 = fmaf(e1, cur.y, a1);
        a2 = fmaf(e2, cur.z, a2); a3 = fmaf(e3, cur.w, a3);
        cur = nxt;
    }
    sS[threadIdx.x] = make_float4(s0, s1, s2, s3);
    sW[threadIdx.x] = make_float4(a0, a1, a2, a3);
    __syncthreads();
    if (threadIdx.x < 64) {
        float4 S = sS[threadIdx.x];
        float4 W = sW[threadIdx.x];
        #pragma unroll
        for (int j = 1; j < 4; ++j) {
            float4 s = sS[j * 64 + threadIdx.x];
            float4 q = sW[j * 64 + threadIdx.x];
            S.x += s.x; S.y += s.y; S.z += s.z; S.w += s.w;
            W.x += q.x; W.y += q.y; W.z += q.z; W.w += q.w;
        }
        int base = (b * TS + ts) * CHN + threadIdx.x * 4;
        *(float4*)(pS + base) = S;
        *(float4*)(pW + base) = W;
    }
}

// ---------------- K4: reduce TS chunks -> c_t ----------------------------------------
__global__ __launch_bounds__(256) void k4_combine(const float* __restrict__ pS,
    const float* __restrict__ pW, float* __restrict__ out_ct, float* __restrict__ At) {
    const int b = blockIdx.x;
    const int ch = threadIdx.x;
    float S = 0.0f, W = 0.0f;
    #pragma unroll
    for (int j = 0; j < TS; ++j) {
        int idx = (b * TS + j) * CHN + ch;
        S += pS[idx];
        W += pW[idx];
    }
    float c = W / S;
    out_ct[b * CHN + ch] = c;
    At[(LL + ch) * BB + b] = c;
}

// ---------------- K5 phase: float2 weights (8+8 dbuf) x LDS-broadcast A --------------
#define K5_FMA(XW) \
    { float4 x = *(const float4*)a; float4 zz = *(const float4*)(a + 4); \
      acc[0].x = fmaf(x.x, XW.x, acc[0].x); acc[0].y = fmaf(x.x, XW.y, acc[0].y); \
      acc[1].x = fmaf(x.y, XW.x, acc[1].x); acc[1].y = fmaf(x.y, XW.y, acc[1].y); \
      acc[2].x = fmaf(x.z, XW.x, acc[2].x); acc[2].y = fmaf(x.z, XW.y, acc[2].y); \
      acc[3].x = fmaf(x.w, XW.x, acc[3].x); acc[3].y = fmaf(x.w, XW.y, acc[3].y); \
      acc[4].x = fmaf(zz.x, XW.x, acc[4].x); acc[4].y = fmaf(zz.x, XW.y, acc[4].y); \
      acc[5].x = fmaf(zz.y, XW.x, acc[5].x); acc[5].y = fmaf(zz.y, XW.y, acc[5].y); \
      acc[6].x = fmaf(zz.z, XW.x, acc[6].x); acc[6].y = fmaf(zz.z, XW.y, acc[6].y); \
      acc[7].x = fmaf(zz.w, XW.x, acc[7].x); acc[7].y = fmaf(zz.w, XW.y, acc[7].y); }

__device__ __forceinline__ void k5_phase(const float* __restrict__ W, int kn,
    const float* sAt, float2 acc[8]) {
    float2 wa[8], wb[8];
    #pragma unroll
    for (int j = 0; j < 8; ++j) wa[j] = *(const float2*)(W + (size_t)j * VV);
    for (int k = 0; k < kn; k += 16) {
        #pragma unroll
        for (int j = 0; j < 8; ++j) wb[j] = *(const float2*)(W + (size_t)(k + 8 + j) * VV);
        #pragma unroll
        for (int j = 0; j < 8; ++j) {
            const float* a = sAt + (size_t)(k + j) * 32;
            K5_FMA(wa[j]);
        }
        if (k + 16 < kn) {
            #pragma unroll
            for (int j = 0; j < 8; ++j) wa[j] = *(const float2*)(W + (size_t)(k + 16 + j) * VV);
        }
        #pragma unroll
        for (int j = 0; j < 8; ++j) {
            const float* a = sAt + (size_t)(k + 8 + j) * 32;
            K5_FMA(wb[j]);
        }
    }
}

// ---------------- K5: exp(logits) into O + per-block row partials --------------------
// grid (250 v-tiles, 2 b-halves) x 256 thr. At slice (384x32=48KB) in LDS.
__global__ __launch_bounds__(256) void k5_logits(const float* __restrict__ Wo,
    const float* __restrict__ Wct2, const float* __restrict__ At,
    float* __restrict__ outO, float* __restrict__ psum) {
    __shared__ float sAt[384][32];     // 48 KB
    const int y = blockIdx.y;
    const int t = threadIdx.x;

    #pragma unroll
    for (int f = t; f < 3072; f += 256) {         // 3072 float4 = 12288 floats
        int k  = f >> 3;
        int c4 = (f & 7) * 4;
        *(float4*)&sAt[k][c4] = *(const float4*)(At + (size_t)k * BB + y * 32 + c4);
    }
    __syncthreads();

    const int lane = t & 63;
    const int v2   = blockIdx.x * 128 + lane * 2;
    const int w8   = (t >> 6) * 8;                // local b of this wave
    float2 acc[8];
    #pragma unroll
    for (int i = 0; i < 8; ++i) acc[i] = make_float2(0.0f, 0.0f);

    k5_phase(Wo + v2, LL, &sAt[0][0] + w8, acc);
    k5_phase(Wct2 + v2, CHN, &sAt[LL][0] + w8, acc);

    const int gb = y * 32 + w8;
    float ps[8];
    #pragma unroll
    for (int i = 0; i < 8; ++i) {
        float2 ex = make_float2(__expf(acc[i].x), __expf(acc[i].y));  // logits bounded
        *(float2*)(outO + (size_t)(gb + i) * VV + v2) = ex;
        float s = ex.x + ex.y;
        #pragma unroll
        for (int m = 32; m > 0; m >>= 1) s += __shfl_xor(s, m, 64);
        ps[i] = s;
    }
    if (lane == 0) {
        #pragma unroll
        for (int i = 0; i < 8; ++i) psum[blockIdx.x * BB + gb + i] = ps[i];
    }
}

// ---------------- K5b: rowsum[b] = sum over 250 psum chunks (1 block) ----------------
__global__ __launch_bounds__(256) void k5b_rowsum(const float* __restrict__ psum,
                                                  float* __restrict__ rowsum) {
    __shared__ float red[256];
    const int t = threadIdx.x;
    const int b = t & 63;
    const int q = t >> 6;                 // 0..3
    float s = 0.0f;
    for (int x = q; x < NC1; x += 4) s += psum[x * BB + b];
    red[t] = s;
    __syncthreads();
    if (t < 64) rowsum[b] = red[b] + red[64 + b] + red[128 + b] + red[192 + b];
}

// ---------------- K5c: normalize: out = exp_stored / rowsum[row] ---------------------
__global__ __launch_bounds__(256) void k5c_norm(float* __restrict__ O,
                                                const float* __restrict__ rowsum) {
    const int gid = blockIdx.x * 256 + threadIdx.x;      // 512000 float4's
    float4* O4 = (float4*)O;
    const u32 row = ((u32)gid * 4u) / (u32)VV;
    const float inv = fast_rcp(rowsum[row]);
    float4 f = O4[gid];
    f.x *= inv; f.y *= inv; f.z *= inv; f.w *= inv;
    O4[gid] = f;
}

extern "C" void kernel_launch(void* const* d_in, const int* in_sizes, int n_in,
                              void* d_out, int out_size, void* d_ws, size_t ws_size,
                              hipStream_t stream) {
    (void)in_sizes; (void)n_in; (void)out_size; (void)ws_size;
    const float* pcv       = (const float*)d_in[0];
    const float* F         = (const float*)d_in[1];
    const float* prev_char = (const float*)d_in[2];
    const float* state_h   = (const float*)d_in[3];
    const float* state_c   = (const float*)d_in[4];
    const float* Wc        = (const float*)d_in[5];
    const float* Wct1      = (const float*)d_in[6];
    const float* Wo        = (const float*)d_in[7];
    const float* Wct2      = (const float*)d_in[8];
    const float* lstm_k    = (const float*)d_in[9];
    const float* lstm_r    = (const float*)d_in[10];
    const float* W_h       = (const float*)d_in[11];
    const float* Vattn     = (const float*)d_in[12];

    // outputs: float32, concatenated flat in return order
    float* outO  = (float*)d_out;                  // [64][32000]
    float* outCt = outO + (size_t)BB * VV;         // [64][256]
    float* outH  = outCt + (size_t)BB * CHN;       // [64][128]
    float* outC  = outH + (size_t)BB * LL;         // [64][128]

    float* ws     = (float*)d_ws;
    float* part   = ws;                            // 250*16000... 250*64*64 = 1,024,000 f
    float* pS     = part + (size_t)NC1 * BB * EE;  // 64*16*256 = 262,144 f
    float* pW     = pS + (size_t)BB * TS * CHN;    // 262,144 f
    float* At     = pW + (size_t)BB * TS * CHN;    // 384*64   = 24,576 f
    float* Htfm   = At + (LL + CHN) * BB;          // 16,384 f
    float* psum   = Htfm + (size_t)BB * CHN;       // 250*64 = 16,000 f
    float* rowsum = psum + (size_t)NC1 * BB;       // 64 f

    hipLaunchKernelGGL(k1_stage1, dim3(NC1, 2), dim3(256), 0, stream, prev_char, Wc, part);
    hipLaunchKernelGGL(k2_lstm, dim3(BB), dim3(512), 0, stream, part, pcv, state_h,
                       state_c, Wct1, lstm_k, lstm_r, W_h, outH, outC, At, Htfm);
    hipLaunchKernelGGL(k3_attn, dim3(BB, TS), dim3(256), 0, stream, F, Htfm, Vattn, pS, pW);
    hipLaunchKernelGGL(k4_combine, dim3(BB), dim3(256), 0, stream, pS, pW, outCt, At);
    hipLaunchKernelGGL(k5_logits, dim3(NC1, 2), dim3(256), 0, stream, Wo, Wct2, At, outO, psum);
    hipLaunchKernelGGL(k5b_rowsum, dim3(1), dim3(256), 0, stream, psum, rowsum);
    hipLaunchKernelGGL(k5c_norm, dim3((BB * VV / 4) / 256), dim3(256), 0, stream, outO, rowsum);
}

// Round 9
// 233.698 us; speedup vs baseline: 1.0809x; 1.0809x over previous
//
#include <hip/hip_runtime.h>
#include <hip/hip_bf16.h>

#define BB 64
#define TT 1024
#define CHN 256
#define VV 32000
#define EE 64
#define LL 128
#define NC1 250      // k1 k-chunks (250*128 = 32000)
#define KC1 128
#define TS 16        // attention t-chunks (64 t each)

typedef unsigned short u16;
typedef unsigned int u32;
typedef __attribute__((ext_vector_type(8))) short short8;
typedef __attribute__((ext_vector_type(16))) float f32x16;

__device__ __forceinline__ float fast_rcp(float x) { return __builtin_amdgcn_rcpf(x); }
__device__ __forceinline__ float tanh_fast(float y) {
    float e = __expf(2.0f * y);              // inf/0 limits give +-1 correctly
    return 1.0f - 2.0f * fast_rcp(1.0f + e);
}
__device__ __forceinline__ float sigmoid_fast(float x) {
    return fast_rcp(1.0f + __expf(-x));
}
__device__ __forceinline__ u16 f2bf(float f) {
    u32 u = __float_as_uint(f);
    return (u16)((u + 0x7fffu + ((u >> 16) & 1u)) >> 16);    // RNE
}
__device__ __forceinline__ u32 pack_bf2(float lo, float hi) {
    return (u32)f2bf(lo) | ((u32)f2bf(hi) << 16);
}

// ---------------- K1: prev_char[64,32000] @ Wc[32000,64] -> part[b][kc][e] -----------
__global__ __launch_bounds__(256) void k1_stage1(const float* __restrict__ A,
                                                 const float* __restrict__ Wc,
                                                 float* __restrict__ part) {
    __shared__ float sW[KC1][EE];      // 32 KB
    __shared__ float sAT[KC1][32];     // 16 KB, transposed: [k][local_b]
    const int kc = blockIdx.x;
    const int k0 = kc * KC1;
    const int y  = blockIdx.y;
    const int t  = threadIdx.x;

    #pragma unroll
    for (int f = t; f < 2048; f += 256)
        *(float4*)(&sW[0][0] + f * 4) = *(const float4*)(Wc + (size_t)k0 * EE + f * 4);
    {
        const int bl = t & 31;
        const int kq = t >> 5;         // 0..7
        const float* src = A + (size_t)(y * 32 + bl) * VV + k0 + kq * 16;
        #pragma unroll
        for (int j4 = 0; j4 < 4; ++j4) {
            float4 v = *(const float4*)(src + j4 * 4);
            sAT[kq * 16 + j4 * 4 + 0][bl] = v.x;
            sAT[kq * 16 + j4 * 4 + 1][bl] = v.y;
            sAT[kq * 16 + j4 * 4 + 2][bl] = v.z;
            sAT[kq * 16 + j4 * 4 + 3][bl] = v.w;
        }
    }
    __syncthreads();

    const int e  = t & 63;
    const int b0 = (t >> 6) * 8;
    float acc[8];
    #pragma unroll
    for (int i = 0; i < 8; ++i) acc[i] = 0.0f;

    #pragma unroll 4
    for (int k = 0; k < KC1; ++k) {
        float wt = sW[k][e];
        float4 a0 = *(const float4*)&sAT[k][b0];           // uniform -> broadcast
        float4 a1 = *(const float4*)&sAT[k][b0 + 4];
        acc[0] = fmaf(a0.x, wt, acc[0]);
        acc[1] = fmaf(a0.y, wt, acc[1]);
        acc[2] = fmaf(a0.z, wt, acc[2]);
        acc[3] = fmaf(a0.w, wt, acc[3]);
        acc[4] = fmaf(a1.x, wt, acc[4]);
        acc[5] = fmaf(a1.y, wt, acc[5]);
        acc[6] = fmaf(a1.z, wt, acc[6]);
        acc[7] = fmaf(a1.w, wt, acc[7]);
    }
    const int gb = y * 32 + b0;
    #pragma unroll
    for (int i = 0; i < 8; ++i)
        part[((size_t)(gb + i) * NC1 + kc) * EE + e] = acc[i];
}

// ---------------- K2: reduce part + pcv@Wct1, z-GEMM, gates, H_tfm, Apk(h) -----------
__global__ __launch_bounds__(512) void k2_lstm(const float* __restrict__ part,
    const float* __restrict__ pcv, const float* __restrict__ state_h,
    const float* __restrict__ state_c, const float* __restrict__ Wct1,
    const float* __restrict__ lstm_kernel, const float* __restrict__ lstm_rec,
    const float* __restrict__ W_h,
    float* __restrict__ out_newh, float* __restrict__ out_newc,
    u32* __restrict__ Apk, float* __restrict__ Htfm) {
    __shared__ float red[8][EE];
    __shared__ float inp[EE];
    __shared__ float sh[LL];
    __shared__ float z[4 * LL];
    __shared__ float nh[LL];
    const int b = blockIdx.x;
    const int t = threadIdx.x;
    const int e  = t & 63;
    const int g  = t >> 6;          // 0..7

    {
        float s = 0.0f;
        for (int j = g; j < NC1; j += 8)                       // contiguous 64KB window
            s += part[((size_t)b * NC1 + j) * EE + e];
        const int c0 = g * 32;
        #pragma unroll 8
        for (int c = 0; c < 32; ++c)
            s = fmaf(pcv[b * CHN + c0 + c], Wct1[(size_t)(c0 + c) * EE + e], s);
        red[g][e] = s;
    }
    __syncthreads();
    if (t < EE) {
        float s = 0.0f;
        #pragma unroll
        for (int j = 0; j < 8; ++j) s += red[j][t];
        inp[t] = s;
    } else if (t >= 64 && t < 64 + LL) {
        sh[t - 64] = state_h[b * LL + (t - 64)];
    }
    __syncthreads();
    {
        float a = 0.0f;
        #pragma unroll 8
        for (int e2 = 0; e2 < EE; ++e2) a = fmaf(inp[e2], lstm_kernel[e2 * 512 + t], a);
        #pragma unroll 8
        for (int l = 0; l < LL; ++l) a = fmaf(sh[l], lstm_rec[l * 512 + t], a);
        z[t] = a;
    }
    __syncthreads();
    if (t < LL) {
        float zi = z[t], zf = z[LL + t], zg = z[2 * LL + t], zo = z[3 * LL + t];
        float ig = sigmoid_fast(zi);
        float fg = sigmoid_fast(zf);
        float gg = tanh_fast(zg);
        float og = sigmoid_fast(zo);
        float co = state_c[b * LL + t];
        float cn = fg * co + ig * gg;
        float hn = og * tanh_fast(cn);
        out_newc[b * LL + t] = fminf(fmaxf(cn, -10.0f), 10.0f);
        out_newh[b * LL + t] = hn;
        nh[t] = hn;
    }
    __syncthreads();
    if (t < CHN) {
        float a = 0.0f;
        #pragma unroll 8
        for (int l = 0; l < LL; ++l) a = fmaf(nh[l], W_h[l * CHN + t], a);
        Htfm[b * CHN + t] = a;
    } else if (t >= CHN && t < CHN + 64) {
        const int k2i = t - CHN;       // bf16 pair rows 0..63 (h part, k=0..127)
        Apk[(size_t)k2i * BB + b] = pack_bf2(nh[2 * k2i], nh[2 * k2i + 1]);
    }
}

// ---------------- K3: attention partials per (b, ts) ---------------------------------
__global__ __launch_bounds__(256) void k3_attn(const float* __restrict__ F,
    const float* __restrict__ Htfm, const float* __restrict__ Vattn,
    float* __restrict__ pS, float* __restrict__ pW) {
    __shared__ float4 sS[256];
    __shared__ float4 sW[256];
    const int b    = blockIdx.x;
    const int ts   = blockIdx.y;
    const int lane = threadIdx.x & 63;
    const int w    = threadIdx.x >> 6;
    const int ch   = lane * 4;

    float4 h = *(const float4*)(Htfm + b * CHN + ch);
    float4 v = *(const float4*)(Vattn + ch);
    float s0 = 0, s1 = 0, s2 = 0, s3 = 0;
    float a0 = 0, a1 = 0, a2 = 0, a3 = 0;

    const float* Fp = F + ((size_t)b * TT + ts * (TT / TS) + w * 16) * CHN + ch;
    float4 cur = *(const float4*)(Fp);
    #pragma unroll
    for (int t = 0; t < 16; ++t) {
        float4 nxt;
        if (t < 15) nxt = *(const float4*)(Fp + (size_t)(t + 1) * CHN);
        float e0 = __expf(v.x * tanh_fast(h.x + cur.x));
        float e1 = __expf(v.y * tanh_fast(h.y + cur.y));
        float e2 = __expf(v.z * tanh_fast(h.z + cur.z));
        float e3 = __expf(v.w * tanh_fast(h.w + cur.w));
        s0 += e0; s1 += e1; s2 += e2; s3 += e3;
        a0 = fmaf(e0, cur.x, a0); a1 = fmaf(e1, cur.y, a1);
        a2 = fmaf(e2, cur.z, a2); a3 = fmaf(e3, cur.w, a3);
        cur = nxt;
    }
    sS[threadIdx.x] = make_float4(s0, s1, s2, s3);
    sW[threadIdx.x] = make_float4(a0, a1, a2, a3);
    __syncthreads();
    if (threadIdx.x < 64) {
        float4 S = sS[threadIdx.x];
        float4 W = sW[threadIdx.x];
        #pragma unroll
        for (int j = 1; j < 4; ++j) {
            float4 s = sS[j * 64 + threadIdx.x];
            float4 q = sW[j * 64 + threadIdx.x];
            S.x += s.x; S.y += s.y; S.z += s.z; S.w += s.w;
            W.x += q.x; W.y += q.y; W.z += q.z; W.w += q.w;
        }
        int base = (b * TS + ts) * CHN + threadIdx.x * 4;
        *(float4*)(pS + base) = S;
        *(float4*)(pW + base) = W;
    }
}

// ---------------- K4: reduce TS chunks -> c_t + Apk(c) -------------------------------
__global__ __launch_bounds__(256) void k4_combine(const float* __restrict__ pS,
    const float* __restrict__ pW, float* __restrict__ out_ct, u32* __restrict__ Apk) {
    __shared__ float sc[CHN];
    const int b = blockIdx.x;
    const int ch = threadIdx.x;
    float S = 0.0f, W = 0.0f;
    #pragma unroll
    for (int j = 0; j < TS; ++j) {
        int idx = (b * TS + j) * CHN + ch;
        S += pS[idx];
        W += pW[idx];
    }
    float c = W / S;
    out_ct[b * CHN + ch] = c;
    sc[ch] = c;
    __syncthreads();
    if (ch < 128)                      // bf16 pair rows 64..191 (c part, k=128..383)
        Apk[(size_t)(64 + ch) * BB + b] = pack_bf2(sc[2 * ch], sc[2 * ch + 1]);
}

// ---------------- K5: MFMA bf16 logits -> exp into O + per-block row partials --------
// grid (250 v-tiles of 128, 2 b-halves) x 256 thr. Wave computes 32b x 32v, K=384
// via 24 x mfma_f32_32x32x16_bf16. A-frags pre-packed (Apk) in VGPRs; W streamed
// f32 -> truncated bf16, 1-tile-deep prefetch (8 loads in flight).
__global__ __launch_bounds__(256) void k5_logits(const float* __restrict__ Wo,
    const float* __restrict__ Wct2, const u32* __restrict__ Apk,
    float* __restrict__ outO, float* __restrict__ psum) {
    __shared__ float rp[4][32];
    const int t    = threadIdx.x;
    const int lane = t & 63;
    const int wv   = t >> 6;
    const int m    = lane & 31;        // A row / C row-group col ... local b
    const int kq   = lane >> 5;        // k-half select
    const int y    = blockIdx.y;
    const int n0   = blockIdx.x * 128 + wv * 32;
    const int gb0  = y * 32;

    // A fragments: tile tt covers k=16tt..16tt+15; reg r = packed pair k2=8tt+kq*4+r
    u32 af[24][4];
    #pragma unroll
    for (int tt = 0; tt < 24; ++tt) {
        #pragma unroll
        for (int r = 0; r < 4; ++r)
            af[tt][r] = Apk[(size_t)(tt * 8 + kq * 4 + r) * BB + gb0 + m];
    }

    f32x16 acc = {0.0f, 0.0f, 0.0f, 0.0f, 0.0f, 0.0f, 0.0f, 0.0f,
                  0.0f, 0.0f, 0.0f, 0.0f, 0.0f, 0.0f, 0.0f, 0.0f};

    float wbuf[2][8];
    {   // prefetch tile 0 (Wo rows kq*8 .. kq*8+7)
        const float* c0 = Wo + (size_t)(kq * 8) * VV + n0 + m;
        #pragma unroll
        for (int j = 0; j < 8; ++j) wbuf[0][j] = c0[(size_t)j * VV];
    }

    #pragma unroll
    for (int tt = 0; tt < 24; ++tt) {
        if (tt < 23) {                 // prefetch next tile
            const int kn = (tt + 1) * 16 + kq * 8;
            const float* cn = (kn < LL ? Wo + (size_t)kn * VV
                                       : Wct2 + (size_t)(kn - LL) * VV) + n0 + m;
            #pragma unroll
            for (int j = 0; j < 8; ++j) wbuf[(tt + 1) & 1][j] = cn[(size_t)j * VV];
        }
        short8 a, b;
        #pragma unroll
        for (int r = 0; r < 4; ++r) {
            u32 lo = __float_as_uint(wbuf[tt & 1][2 * r]);
            u32 hi = __float_as_uint(wbuf[tt & 1][2 * r + 1]);
            u32 bp = (lo >> 16) | (hi & 0xffff0000u);       // truncate-to-bf16 pair
            u32 ap = af[tt][r];
            a[2 * r]     = (short)(ap & 0xffff);
            a[2 * r + 1] = (short)(ap >> 16);
            b[2 * r]     = (short)(bp & 0xffff);
            b[2 * r + 1] = (short)(bp >> 16);
        }
        acc = __builtin_amdgcn_mfma_f32_32x32x16_bf16(a, b, acc, 0, 0, 0);
    }

    // epilogue: exp, store, row-sum partials (C/D: col=lane&31, row=(r&3)+8(r>>2)+4kq)
    float ex[16];
    #pragma unroll
    for (int r = 0; r < 16; ++r) {
        const int row = (r & 3) + 8 * (r >> 2) + 4 * kq;
        ex[r] = __expf(acc[r]);                             // logits bounded ~|4|
        outO[(size_t)(gb0 + row) * VV + n0 + m] = ex[r];
    }
    #pragma unroll
    for (int r = 0; r < 16; ++r) {                          // sum across 32 cols
        float s = ex[r];
        s += __shfl_xor(s, 1, 64);  s += __shfl_xor(s, 2, 64);
        s += __shfl_xor(s, 4, 64);  s += __shfl_xor(s, 8, 64);
        s += __shfl_xor(s, 16, 64);
        ex[r] = s;
    }
    if (m == 0) {                                           // lanes 0 and 32
        #pragma unroll
        for (int r = 0; r < 16; ++r)
            rp[wv][(r & 3) + 8 * (r >> 2) + 4 * kq] = ex[r];
    }
    __syncthreads();
    if (t < 32)
        psum[(size_t)blockIdx.x * BB + gb0 + t] =
            rp[0][t] + rp[1][t] + rp[2][t] + rp[3][t];
}

// ---------------- K5b: rowsum[b] = sum over 250 psum chunks (1 block) ----------------
__global__ __launch_bounds__(256) void k5b_rowsum(const float* __restrict__ psum,
                                                  float* __restrict__ rowsum) {
    __shared__ float red[256];
    const int t = threadIdx.x;
    const int b = t & 63;
    const int q = t >> 6;                 // 0..3
    float s = 0.0f;
    for (int x = q; x < NC1; x += 4) s += psum[x * BB + b];
    red[t] = s;
    __syncthreads();
    if (t < 64) rowsum[b] = red[b] + red[64 + b] + red[128 + b] + red[192 + b];
}

// ---------------- K5c: normalize: out = exp_stored / rowsum[row] ---------------------
__global__ __launch_bounds__(256) void k5c_norm(float* __restrict__ O,
                                                const float* __restrict__ rowsum) {
    const int gid = blockIdx.x * 256 + threadIdx.x;      // 512000 float4's
    float4* O4 = (float4*)O;
    const u32 row = ((u32)gid * 4u) / (u32)VV;
    const float inv = fast_rcp(rowsum[row]);
    float4 f = O4[gid];
    f.x *= inv; f.y *= inv; f.z *= inv; f.w *= inv;
    O4[gid] = f;
}

extern "C" void kernel_launch(void* const* d_in, const int* in_sizes, int n_in,
                              void* d_out, int out_size, void* d_ws, size_t ws_size,
                              hipStream_t stream) {
    (void)in_sizes; (void)n_in; (void)out_size; (void)ws_size;
    const float* pcv       = (const float*)d_in[0];
    const float* F         = (const float*)d_in[1];
    const float* prev_char = (const float*)d_in[2];
    const float* state_h   = (const float*)d_in[3];
    const float* state_c   = (const float*)d_in[4];
    const float* Wc        = (const float*)d_in[5];
    const float* Wct1      = (const float*)d_in[6];
    const float* Wo        = (const float*)d_in[7];
    const float* Wct2      = (const float*)d_in[8];
    const float* lstm_k    = (const float*)d_in[9];
    const float* lstm_r    = (const float*)d_in[10];
    const float* W_h       = (const float*)d_in[11];
    const float* Vattn     = (const float*)d_in[12];

    // outputs: float32, concatenated flat in return order
    float* outO  = (float*)d_out;                  // [64][32000]
    float* outCt = outO + (size_t)BB * VV;         // [64][256]
    float* outH  = outCt + (size_t)BB * CHN;       // [64][128]
    float* outC  = outH + (size_t)BB * LL;         // [64][128]

    float* ws     = (float*)d_ws;
    float* part   = ws;                            // 250*64*64 = 1,024,000 f
    float* pS     = part + (size_t)NC1 * BB * EE;  // 64*16*256 = 262,144 f
    float* pW     = pS + (size_t)BB * TS * CHN;    // 262,144 f
    float* Htfm   = pW + (size_t)BB * TS * CHN;    // 16,384 f
    float* psum   = Htfm + (size_t)BB * CHN;       // 250*64 = 16,000 f
    float* rowsum = psum + (size_t)NC1 * BB;       // 64 f
    u32*   Apk    = (u32*)(rowsum + BB);           // 192*64 = 12,288 u32

    hipLaunchKernelGGL(k1_stage1, dim3(NC1, 2), dim3(256), 0, stream, prev_char, Wc, part);
    hipLaunchKernelGGL(k2_lstm, dim3(BB), dim3(512), 0, stream, part, pcv, state_h,
                       state_c, Wct1, lstm_k, lstm_r, W_h, outH, outC, Apk, Htfm);
    hipLaunchKernelGGL(k3_attn, dim3(BB, TS), dim3(256), 0, stream, F, Htfm, Vattn, pS, pW);
    hipLaunchKernelGGL(k4_combine, dim3(BB), dim3(256), 0, stream, pS, pW, outCt, Apk);
    hipLaunchKernelGGL(k5_logits, dim3(NC1, 2), dim3(256), 0, stream, Wo, Wct2, Apk, outO, psum);
    hipLaunchKernelGGL(k5b_rowsum, dim3(1), dim3(256), 0, stream, psum, rowsum);
    hipLaunchKernelGGL(k5c_norm, dim3((BB * VV / 4) / 256), dim3(256), 0, stream, outO, rowsum);
}

// Round 10
// 221.424 us; speedup vs baseline: 1.1408x; 1.0554x over previous
//
#include <hip/hip_runtime.h>
#include <hip/hip_bf16.h>

#define BB 64
#define TT 1024
#define CHN 256
#define VV 32000
#define EE 64
#define LL 128
#define NC1 250      // k1 k-chunks (250*128 = 32000)
#define KC1 128
#define TS 16        // attention t-chunks (64 t each)

typedef unsigned short u16;
typedef unsigned int u32;
typedef __attribute__((ext_vector_type(8))) short short8;
typedef __attribute__((ext_vector_type(16))) float f32x16;

__device__ __forceinline__ float fast_rcp(float x) { return __builtin_amdgcn_rcpf(x); }
__device__ __forceinline__ float tanh_fast(float y) {
    float e = __expf(2.0f * y);              // inf/0 limits give +-1 correctly
    return 1.0f - 2.0f * fast_rcp(1.0f + e);
}
__device__ __forceinline__ float sigmoid_fast(float x) {
    return fast_rcp(1.0f + __expf(-x));
}
__device__ __forceinline__ u16 f2bf(float f) {
    u32 u = __float_as_uint(f);
    return (u16)((u + 0x7fffu + ((u >> 16) & 1u)) >> 16);    // RNE
}
__device__ __forceinline__ u32 pack_bf2(float lo, float hi) {
    return (u32)f2bf(lo) | ((u32)f2bf(hi) << 16);
}
__device__ __forceinline__ float bf2f(u16 x) {
    return __uint_as_float(((u32)x) << 16);
}
// Apk index for packed-pair g (k = 2g..2g+1), batch b:
// tile tt = g>>3, kq = (g&7)>>2, reg r = g&3  ->  ((tt*2+kq)*64 + b)*4 + r
__device__ __forceinline__ size_t apk_idx(int g, int b) {
    return ((size_t)(((g >> 3) * 2 + ((g & 7) >> 2)) * 64 + b)) * 4 + (g & 3);
}

// ---------------- K1: prev_char[64,32000] @ Wc[32000,64] -> part[b][kc][e] -----------
__global__ __launch_bounds__(256) void k1_stage1(const float* __restrict__ A,
                                                 const float* __restrict__ Wc,
                                                 float* __restrict__ part) {
    __shared__ float sW[KC1][EE];      // 32 KB
    __shared__ float sAT[KC1][32];     // 16 KB, transposed: [k][local_b]
    const int kc = blockIdx.x;
    const int k0 = kc * KC1;
    const int y  = blockIdx.y;
    const int t  = threadIdx.x;

    #pragma unroll
    for (int f = t; f < 2048; f += 256)
        *(float4*)(&sW[0][0] + f * 4) = *(const float4*)(Wc + (size_t)k0 * EE + f * 4);
    {
        const int bl = t & 31;
        const int kq = t >> 5;         // 0..7
        const float* src = A + (size_t)(y * 32 + bl) * VV + k0 + kq * 16;
        #pragma unroll
        for (int j4 = 0; j4 < 4; ++j4) {
            float4 v = *(const float4*)(src + j4 * 4);
            sAT[kq * 16 + j4 * 4 + 0][bl] = v.x;
            sAT[kq * 16 + j4 * 4 + 1][bl] = v.y;
            sAT[kq * 16 + j4 * 4 + 2][bl] = v.z;
            sAT[kq * 16 + j4 * 4 + 3][bl] = v.w;
        }
    }
    __syncthreads();

    const int e  = t & 63;
    const int b0 = (t >> 6) * 8;
    float acc[8];
    #pragma unroll
    for (int i = 0; i < 8; ++i) acc[i] = 0.0f;

    #pragma unroll 4
    for (int k = 0; k < KC1; ++k) {
        float wt = sW[k][e];
        float4 a0 = *(const float4*)&sAT[k][b0];           // uniform -> broadcast
        float4 a1 = *(const float4*)&sAT[k][b0 + 4];
        acc[0] = fmaf(a0.x, wt, acc[0]);
        acc[1] = fmaf(a0.y, wt, acc[1]);
        acc[2] = fmaf(a0.z, wt, acc[2]);
        acc[3] = fmaf(a0.w, wt, acc[3]);
        acc[4] = fmaf(a1.x, wt, acc[4]);
        acc[5] = fmaf(a1.y, wt, acc[5]);
        acc[6] = fmaf(a1.z, wt, acc[6]);
        acc[7] = fmaf(a1.w, wt, acc[7]);
    }
    const int gb = y * 32 + b0;
    #pragma unroll
    for (int i = 0; i < 8; ++i)
        part[((size_t)(gb + i) * NC1 + kc) * EE + e] = acc[i];
}

// ---------------- K2: reduce part + pcv@Wct1, z-GEMM, gates, H_tfm, Apk(h) -----------
__global__ __launch_bounds__(512) void k2_lstm(const float* __restrict__ part,
    const float* __restrict__ pcv, const float* __restrict__ state_h,
    const float* __restrict__ state_c, const float* __restrict__ Wct1,
    const float* __restrict__ lstm_kernel, const float* __restrict__ lstm_rec,
    const float* __restrict__ W_h,
    float* __restrict__ out_newh, float* __restrict__ out_newc,
    u32* __restrict__ Apk, float* __restrict__ Htfm) {
    __shared__ float red[8][EE];
    __shared__ float inp[EE];
    __shared__ float sh[LL];
    __shared__ float z[4 * LL];
    __shared__ float nh[LL];
    const int b = blockIdx.x;
    const int t = threadIdx.x;
    const int e  = t & 63;
    const int g  = t >> 6;          // 0..7

    {
        float s = 0.0f;
        #pragma unroll 4
        for (int j = g; j < NC1; j += 8)                       // contiguous 64KB window
            s += part[((size_t)b * NC1 + j) * EE + e];
        const int c0 = g * 32;
        #pragma unroll 8
        for (int c = 0; c < 32; ++c)
            s = fmaf(pcv[b * CHN + c0 + c], Wct1[(size_t)(c0 + c) * EE + e], s);
        red[g][e] = s;
    }
    __syncthreads();
    if (t < EE) {
        float s = 0.0f;
        #pragma unroll
        for (int j = 0; j < 8; ++j) s += red[j][t];
        inp[t] = s;
    } else if (t >= 64 && t < 64 + LL) {
        sh[t - 64] = state_h[b * LL + (t - 64)];
    }
    __syncthreads();
    {
        float a = 0.0f;
        #pragma unroll 8
        for (int e2 = 0; e2 < EE; ++e2) a = fmaf(inp[e2], lstm_kernel[e2 * 512 + t], a);
        #pragma unroll 8
        for (int l = 0; l < LL; ++l) a = fmaf(sh[l], lstm_rec[l * 512 + t], a);
        z[t] = a;
    }
    __syncthreads();
    if (t < LL) {
        float zi = z[t], zf = z[LL + t], zg = z[2 * LL + t], zo = z[3 * LL + t];
        float ig = sigmoid_fast(zi);
        float fg = sigmoid_fast(zf);
        float gg = tanh_fast(zg);
        float og = sigmoid_fast(zo);
        float co = state_c[b * LL + t];
        float cn = fg * co + ig * gg;
        float hn = og * tanh_fast(cn);
        out_newc[b * LL + t] = fminf(fmaxf(cn, -10.0f), 10.0f);
        out_newh[b * LL + t] = hn;
        nh[t] = hn;
    }
    __syncthreads();
    if (t < CHN) {
        float a = 0.0f;
        #pragma unroll 8
        for (int l = 0; l < LL; ++l) a = fmaf(nh[l], W_h[l * CHN + t], a);
        Htfm[b * CHN + t] = a;
    } else if (t >= CHN && t < CHN + 64) {
        const int gp = t - CHN;        // packed pairs 0..63 (h part, k=0..127)
        Apk[apk_idx(gp, b)] = pack_bf2(nh[2 * gp], nh[2 * gp + 1]);
    }
}

// ---------------- K3: attention partials per (b, ts) ---------------------------------
__global__ __launch_bounds__(256) void k3_attn(const float* __restrict__ F,
    const float* __restrict__ Htfm, const float* __restrict__ Vattn,
    float* __restrict__ pS, float* __restrict__ pW) {
    __shared__ float4 sS[256];
    __shared__ float4 sW[256];
    const int b    = blockIdx.x;
    const int ts   = blockIdx.y;
    const int lane = threadIdx.x & 63;
    const int w    = threadIdx.x >> 6;
    const int ch   = lane * 4;

    float4 h = *(const float4*)(Htfm + b * CHN + ch);
    float4 v = *(const float4*)(Vattn + ch);
    float s0 = 0, s1 = 0, s2 = 0, s3 = 0;
    float a0 = 0, a1 = 0, a2 = 0, a3 = 0;

    const float* Fp = F + ((size_t)b * TT + ts * (TT / TS) + w * 16) * CHN + ch;
    float4 cur = *(const float4*)(Fp);
    #pragma unroll
    for (int t = 0; t < 16; ++t) {
        float4 nxt;
        if (t < 15) nxt = *(const float4*)(Fp + (size_t)(t + 1) * CHN);
        float e0 = __expf(v.x * tanh_fast(h.x + cur.x));
        float e1 = __expf(v.y * tanh_fast(h.y + cur.y));
        float e2 = __expf(v.z * tanh_fast(h.z + cur.z));
        float e3 = __expf(v.w * tanh_fast(h.w + cur.w));
        s0 += e0; s1 += e1; s2 += e2; s3 += e3;
        a0 = fmaf(e0, cur.x, a0); a1 = fmaf(e1, cur.y, a1);
        a2 = fmaf(e2, cur.z, a2); a3 = fmaf(e3, cur.w, a3);
        cur = nxt;
    }
    sS[threadIdx.x] = make_float4(s0, s1, s2, s3);
    sW[threadIdx.x] = make_float4(a0, a1, a2, a3);
    __syncthreads();
    if (threadIdx.x < 64) {
        float4 S = sS[threadIdx.x];
        float4 W = sW[threadIdx.x];
        #pragma unroll
        for (int j = 1; j < 4; ++j) {
            float4 s = sS[j * 64 + threadIdx.x];
            float4 q = sW[j * 64 + threadIdx.x];
            S.x += s.x; S.y += s.y; S.z += s.z; S.w += s.w;
            W.x += q.x; W.y += q.y; W.z += q.z; W.w += q.w;
        }
        int base = (b * TS + ts) * CHN + threadIdx.x * 4;
        *(float4*)(pS + base) = S;
        *(float4*)(pW + base) = W;
    }
}

// ---------------- K4: reduce TS chunks -> c_t + Apk(c) -------------------------------
__global__ __launch_bounds__(256) void k4_combine(const float* __restrict__ pS,
    const float* __restrict__ pW, float* __restrict__ out_ct, u32* __restrict__ Apk) {
    __shared__ float sc[CHN];
    const int b = blockIdx.x;
    const int ch = threadIdx.x;
    float S = 0.0f, W = 0.0f;
    #pragma unroll
    for (int j = 0; j < TS; ++j) {
        int idx = (b * TS + j) * CHN + ch;
        S += pS[idx];
        W += pW[idx];
    }
    float c = W / S;
    out_ct[b * CHN + ch] = c;
    sc[ch] = c;
    __syncthreads();
    if (ch < 128)                      // packed pairs 64..191 (c part, k=128..383)
        Apk[apk_idx(64 + ch, b)] = pack_bf2(sc[2 * ch], sc[2 * ch + 1]);
}

// ---------------- K5: MFMA bf16 logits -> bf16 exp + per-block row partials ----------
// grid (250 v-tiles of 128, 2 b-halves) x 256 thr. Wave computes 32b x 32v, K=384
// via 24 x mfma_f32_32x32x16_bf16. A frags: one uint4 per tile (coalesced). W
// streamed f32 -> truncated bf16, 1-tile-deep prefetch.
__global__ __launch_bounds__(256) void k5_logits(const float* __restrict__ Wo,
    const float* __restrict__ Wct2, const u32* __restrict__ Apk,
    u16* __restrict__ expb, float* __restrict__ psum) {
    __shared__ float rp[4][32];
    const int t    = threadIdx.x;
    const int lane = t & 63;
    const int wv   = t >> 6;
    const int m    = lane & 31;        // local b (A row / C col)
    const int kq   = lane >> 5;        // k-half select
    const int y    = blockIdx.y;
    const int n0   = blockIdx.x * 128 + wv * 32;
    const int gb0  = y * 32;

    uint4 af[24];
    #pragma unroll
    for (int tt = 0; tt < 24; ++tt)
        af[tt] = *(const uint4*)&Apk[((size_t)((tt * 2 + kq) * 64) + gb0 + m) * 4];

    f32x16 acc = {0.0f, 0.0f, 0.0f, 0.0f, 0.0f, 0.0f, 0.0f, 0.0f,
                  0.0f, 0.0f, 0.0f, 0.0f, 0.0f, 0.0f, 0.0f, 0.0f};

    float wbuf[2][8];
    {   // prefetch tile 0 (Wo rows kq*8 .. kq*8+7)
        const float* c0 = Wo + (size_t)(kq * 8) * VV + n0 + m;
        #pragma unroll
        for (int j = 0; j < 8; ++j) wbuf[0][j] = c0[(size_t)j * VV];
    }

    #pragma unroll
    for (int tt = 0; tt < 24; ++tt) {
        if (tt < 23) {                 // prefetch next tile
            const int kn = (tt + 1) * 16 + kq * 8;
            const float* cn = (kn < LL ? Wo + (size_t)kn * VV
                                       : Wct2 + (size_t)(kn - LL) * VV) + n0 + m;
            #pragma unroll
            for (int j = 0; j < 8; ++j) wbuf[(tt + 1) & 1][j] = cn[(size_t)j * VV];
        }
        short8 a, b;
        u32 ax = af[tt].x, ay = af[tt].y, az = af[tt].z, aw = af[tt].w;
        #pragma unroll
        for (int r = 0; r < 4; ++r) {
            u32 lo = __float_as_uint(wbuf[tt & 1][2 * r]);
            u32 hi = __float_as_uint(wbuf[tt & 1][2 * r + 1]);
            u32 bp = (lo >> 16) | (hi & 0xffff0000u);       // truncate-to-bf16 pair
            u32 ap = (r == 0) ? ax : (r == 1) ? ay : (r == 2) ? az : aw;
            a[2 * r]     = (short)(ap & 0xffff);
            a[2 * r + 1] = (short)(ap >> 16);
            b[2 * r]     = (short)(bp & 0xffff);
            b[2 * r + 1] = (short)(bp >> 16);
        }
        acc = __builtin_amdgcn_mfma_f32_32x32x16_bf16(a, b, acc, 0, 0, 0);
    }

    // epilogue: exp (f32), bf16 store, row partials. C/D: col=m, row=(r&3)+8(r>>2)+4kq
    float ex[16];
    #pragma unroll
    for (int r = 0; r < 16; ++r) {
        const int row = (r & 3) + 8 * (r >> 2) + 4 * kq;
        ex[r] = __expf(acc[r]);                             // logits bounded ~|4|
        expb[(size_t)(gb0 + row) * VV + n0 + m] = f2bf(ex[r]);
    }
    #pragma unroll
    for (int r = 0; r < 16; ++r) {                          // sum across 32 cols
        float s = ex[r];
        s += __shfl_xor(s, 1, 64);  s += __shfl_xor(s, 2, 64);
        s += __shfl_xor(s, 4, 64);  s += __shfl_xor(s, 8, 64);
        s += __shfl_xor(s, 16, 64);
        ex[r] = s;
    }
    if (m == 0) {                                           // lanes 0 and 32
        #pragma unroll
        for (int r = 0; r < 16; ++r)
            rp[wv][(r & 3) + 8 * (r >> 2) + 4 * kq] = ex[r];
    }
    __syncthreads();
    if (t < 32)
        psum[(size_t)blockIdx.x * BB + gb0 + t] =
            rp[0][t] + rp[1][t] + rp[2][t] + rp[3][t];
}

// ---------------- K5c: rowsum (in-block) + normalize bf16 exp -> f32 O ---------------
// grid (64 rows, 4 segs of 8000 v) x 256 thr.
__global__ __launch_bounds__(256) void k5c_norm(const u16* __restrict__ expb,
    const float* __restrict__ psum, float* __restrict__ O) {
    __shared__ float red[256];
    const int b   = blockIdx.x;
    const int seg = blockIdx.y;
    const int t   = threadIdx.x;

    red[t] = (t < NC1) ? psum[(size_t)t * BB + b] : 0.0f;
    __syncthreads();
    #pragma unroll
    for (int off = 128; off > 0; off >>= 1) {
        if (t < off) red[t] += red[t + off];
        __syncthreads();
    }
    const float inv = fast_rcp(red[0]);

    const u16* src = expb + (size_t)b * VV + seg * 8000;
    float* dst     = O + (size_t)b * VV + seg * 8000;
    #pragma unroll 2
    for (int i = t; i < 2000; i += 256) {            // 2000 x (4 bf16)
        uint2 pk = *(const uint2*)(src + i * 4);
        float4 f;
        f.x = bf2f((u16)(pk.x & 0xffff)) * inv;
        f.y = bf2f((u16)(pk.x >> 16)) * inv;
        f.z = bf2f((u16)(pk.y & 0xffff)) * inv;
        f.w = bf2f((u16)(pk.y >> 16)) * inv;
        *(float4*)(dst + i * 4) = f;
    }
}

extern "C" void kernel_launch(void* const* d_in, const int* in_sizes, int n_in,
                              void* d_out, int out_size, void* d_ws, size_t ws_size,
                              hipStream_t stream) {
    (void)in_sizes; (void)n_in; (void)out_size; (void)ws_size;
    const float* pcv       = (const float*)d_in[0];
    const float* F         = (const float*)d_in[1];
    const float* prev_char = (const float*)d_in[2];
    const float* state_h   = (const float*)d_in[3];
    const float* state_c   = (const float*)d_in[4];
    const float* Wc        = (const float*)d_in[5];
    const float* Wct1      = (const float*)d_in[6];
    const float* Wo        = (const float*)d_in[7];
    const float* Wct2      = (const float*)d_in[8];
    const float* lstm_k    = (const float*)d_in[9];
    const float* lstm_r    = (const float*)d_in[10];
    const float* W_h       = (const float*)d_in[11];
    const float* Vattn     = (const float*)d_in[12];

    // outputs: float32, concatenated flat in return order
    float* outO  = (float*)d_out;                  // [64][32000]
    float* outCt = outO + (size_t)BB * VV;         // [64][256]
    float* outH  = outCt + (size_t)BB * CHN;       // [64][128]
    float* outC  = outH + (size_t)BB * LL;         // [64][128]

    float* ws     = (float*)d_ws;
    float* part   = ws;                            // 250*64*64 = 1,024,000 f
    float* pS     = part + (size_t)NC1 * BB * EE;  // 64*16*256 = 262,144 f
    float* pW     = pS + (size_t)BB * TS * CHN;    // 262,144 f
    float* Htfm   = pW + (size_t)BB * TS * CHN;    // 16,384 f
    float* psum   = Htfm + (size_t)BB * CHN;       // 250*64 = 16,000 f
    u32*   Apk    = (u32*)(psum + (size_t)NC1 * BB);   // 24*2*64*4 = 12,288 u32
    u16*   expb   = (u16*)(Apk + 12288);           // 64*32000 u16 = 4.1 MB

    hipLaunchKernelGGL(k1_stage1, dim3(NC1, 2), dim3(256), 0, stream, prev_char, Wc, part);
    hipLaunchKernelGGL(k2_lstm, dim3(BB), dim3(512), 0, stream, part, pcv, state_h,
                       state_c, Wct1, lstm_k, lstm_r, W_h, outH, outC, Apk, Htfm);
    hipLaunchKernelGGL(k3_attn, dim3(BB, TS), dim3(256), 0, stream, F, Htfm, Vattn, pS, pW);
    hipLaunchKernelGGL(k4_combine, dim3(BB), dim3(256), 0, stream, pS, pW, outCt, Apk);
    hipLaunchKernelGGL(k5_logits, dim3(NC1, 2), dim3(256), 0, stream, Wo, Wct2, Apk, expb, psum);
    hipLaunchKernelGGL(k5c_norm, dim3(BB, 4), dim3(256), 0, stream, expb, psum, outO);
}